// Round 15
// baseline (87.883 us; speedup 1.0000x reference)
//
#include <hip/hip_runtime.h>
#include <stdint.h>

typedef _Float16 f16x8 __attribute__((ext_vector_type(8)));
typedef _Float16 f16x4 __attribute__((ext_vector_type(4)));
typedef __fp16 half2_t __attribute__((ext_vector_type(2)));
typedef float f32x4 __attribute__((ext_vector_type(4)));

#define LOG2E 1.44269504088896340736f
#define NEGINF (-1e16f)

constexpr int kN = 4096;   // nodes
constexpr int kD = 64;     // feature dim
constexpr int kB = 8;      // batch

// ---------------------------------------------------------------------------
// Kernel 1: h[row][d] = sum_c x[row][c] * W[d][c]  (f32 math, f16 store)
//           also writes hT[b][d][n] via LDS transpose (coalesced stores)
// ---------------------------------------------------------------------------
__global__ __launch_bounds__(256) void hproj_kernel(const float* __restrict__ x,
                                                    const float* __restrict__ W,
                                                    _Float16* __restrict__ hout,
                                                    _Float16* __restrict__ hTout)
{
    __shared__ float Wt[64][64];   // Wt[c][d] = W[d][c]
    __shared__ float xs[64][65];
    __shared__ _Float16 ht[64][68];  // h tile for transpose, padded

    const int tid = threadIdx.x;
    const int r   = tid >> 2;          // 0..63
    const int c0  = (tid & 3) * 16;    // 0,16,32,48

    #pragma unroll
    for (int j = 0; j < 16; j += 4) {
        const float4 v = *(const float4*)(W + r * 64 + c0 + j);
        Wt[c0 + j + 0][r] = v.x;
        Wt[c0 + j + 1][r] = v.y;
        Wt[c0 + j + 2][r] = v.z;
        Wt[c0 + j + 3][r] = v.w;
    }
    const long rowbase = (long)blockIdx.x * 64;
    #pragma unroll
    for (int j = 0; j < 16; j += 4) {
        const float4 v = *(const float4*)(x + (rowbase + r) * 64 + c0 + j);
        xs[r][c0 + j + 0] = v.x;
        xs[r][c0 + j + 1] = v.y;
        xs[r][c0 + j + 2] = v.z;
        xs[r][c0 + j + 3] = v.w;
    }
    __syncthreads();

    const int d0 = (tid & 3) * 16;
    f32x4 acc[4] = {{0.f,0.f,0.f,0.f},{0.f,0.f,0.f,0.f},{0.f,0.f,0.f,0.f},{0.f,0.f,0.f,0.f}};
    #pragma unroll 4
    for (int c = 0; c < 64; ++c) {
        const float xv = xs[r][c];
        const f32x4* wrow = (const f32x4*)&Wt[c][d0];
        #pragma unroll
        for (int k = 0; k < 4; ++k) acc[k] += wrow[k] * xv;
    }
    f16x8 o0, o1;
    #pragma unroll
    for (int j = 0; j < 8; ++j) {
        o0[j] = (_Float16)acc[j >> 2][j & 3];
        o1[j] = (_Float16)acc[2 + (j >> 2)][j & 3];
    }
    *(f16x8*)(hout + (rowbase + r) * 64 + d0)     = o0;
    *(f16x8*)(hout + (rowbase + r) * 64 + d0 + 8) = o1;

    // LDS transpose for hT
    #pragma unroll
    for (int j = 0; j < 8; ++j) {
        ht[r][d0 + j]     = o0[j];
        ht[r][d0 + 8 + j] = o1[j];
    }
    __syncthreads();

    const int bb = blockIdx.x >> 6;                 // 64 blocks per batch
    const int n0 = (int)(rowbase & (kN - 1));
    const int dr = tid >> 2;                        // output d row
    const int c4 = (tid & 3) * 16;                  // n-column group
    f16x8 t0, t1;
    #pragma unroll
    for (int j = 0; j < 8; ++j) {
        t0[j] = ht[c4 + j][dr];
        t1[j] = ht[c4 + 8 + j][dr];
    }
    _Float16* dst = hTout + (long)bb * kD * kN + (long)dr * kN + n0 + c4;
    *(f16x8*)(dst)     = t0;
    *(f16x8*)(dst + 8) = t1;
}

// ---------------------------------------------------------------------------
// Kernel 2 (fused): graph (int32 0/1) -> per-slot 64-bit LANE masks directly.
// wm[(q16*64 + kv64)*16 + s]: bit for lane l=(lg*16+ll) =
//   graph[q16*16+ll][kv64*64 + (t>=2?32:0) + 8*lg + 4*(t&1) + rr],  s=t*4+rr
// Wave wv handles pair = blockIdx.x*4+wv. Lane reads its 16 graph ints
// (4 int4 loads), ballots 16 slots, select-tree, lanes 0..15 store.
// ---------------------------------------------------------------------------
__global__ __launch_bounds__(256) void graphmask_kernel(const int* __restrict__ g,
                                                        uint64_t* __restrict__ wmout)
{
    const int tid  = threadIdx.x;
    const int wv   = tid >> 6;
    const int lane = tid & 63;
    const int ll   = lane & 15;
    const int lg   = lane >> 4;
    const int pair = blockIdx.x * 4 + wv;          // 0..16383
    const int q16  = pair >> 6;
    const int kv64 = pair & 63;

    const int* gr = g + (long)(q16 * 16 + ll) * kN + kv64 * 64 + 8 * lg;
    const int4 u0 = *(const int4*)(gr);            // cols 8lg+0..3
    const int4 u1 = *(const int4*)(gr + 4);        // cols 8lg+4..7
    const int4 u2 = *(const int4*)(gr + 32);       // cols 32+8lg+0..3
    const int4 u3 = *(const int4*)(gr + 36);       // cols 32+8lg+4..7

    int gv[16];
    gv[0] = u0.x;  gv[1] = u0.y;  gv[2] = u0.z;  gv[3] = u0.w;
    gv[4] = u1.x;  gv[5] = u1.y;  gv[6] = u1.z;  gv[7] = u1.w;
    gv[8] = u2.x;  gv[9] = u2.y;  gv[10] = u2.z;  gv[11] = u2.w;
    gv[12] = u3.x; gv[13] = u3.y; gv[14] = u3.z;  gv[15] = u3.w;

    uint64_t Wb[16];
    #pragma unroll
    for (int s = 0; s < 16; ++s) {
        const int t = s >> 2, rr = s & 3;
        const int j = (t >= 2 ? 8 : 0) + 4 * (t & 1) + rr;   // index into gv
        Wb[s] = __ballot(gv[j] != 0);
    }

    const int s = lane;
    uint64_t a0 = (s & 1) ? Wb[1]  : Wb[0];
    uint64_t a1 = (s & 1) ? Wb[3]  : Wb[2];
    uint64_t a2 = (s & 1) ? Wb[5]  : Wb[4];
    uint64_t a3 = (s & 1) ? Wb[7]  : Wb[6];
    uint64_t a4 = (s & 1) ? Wb[9]  : Wb[8];
    uint64_t a5 = (s & 1) ? Wb[11] : Wb[10];
    uint64_t a6 = (s & 1) ? Wb[13] : Wb[12];
    uint64_t a7 = (s & 1) ? Wb[15] : Wb[14];
    uint64_t b0 = (s & 2) ? a1 : a0;
    uint64_t b1 = (s & 2) ? a3 : a2;
    uint64_t b2 = (s & 2) ? a5 : a4;
    uint64_t b3 = (s & 2) ? a7 : a6;
    uint64_t c0 = (s & 4) ? b1 : b0;
    uint64_t c1 = (s & 4) ? b3 : b2;
    uint64_t v  = (s & 8) ? c1 : c0;
    if (lane < 16) wmout[(long)pair * 16 + lane] = v;
}

// ---------------------------------------------------------------------------
// Kernel 3: swapped-operand flash attention, 32-q waves (r14-proven body).
// grid (16, 8, KS), 512 thr (8 waves); wave handles 32 q rows (block: 256).
// ks=8 -> 1024 blocks = 4 resident blocks/CU = 32 waves/CU (the HW max).
// ---------------------------------------------------------------------------
__global__ __launch_bounds__(512, 4) void attn_kernel(const _Float16* __restrict__ h,
                                                      const _Float16* __restrict__ hT,
                                                      const uint64_t* __restrict__ wmask,
                                                      const float* __restrict__ bias,
                                                      float* __restrict__ outp,
                                                      _Float16* __restrict__ pO,
                                                      float* __restrict__ pml,
                                                      int kvlen)
{
    __shared__ alignas(16) char Kl[2][8192];
    __shared__ alignas(16) char Vt[2][8192];

    const int b     = blockIdx.y;
    const int split = blockIdx.z;
    const int q0    = blockIdx.x * 256;
    const int tid   = threadIdx.x;
    const int wave  = tid >> 6;
    const int lane  = tid & 63;
    const int lg    = lane >> 4;   // 0..3
    const int ll    = lane & 15;   // 0..15

    const _Float16* hb  = h  + (long)b * kN * kD;
    const _Float16* hTb = hT + (long)b * kD * kN;
    const int kv_base = split * kvlen;
    const int NT      = kvlen / 64;

    // Dual Q fragments: frag A = q rows [wave*32, +16), frag B = [+16, +32)
    const int qA = q0 + wave * 32 + ll;
    const int qB = qA + 16;
    const f16x8 qfA0 = *(const f16x8*)(hb + qA * 64 + lg * 8);
    const f16x8 qfA1 = *(const f16x8*)(hb + qA * 64 + 32 + lg * 8);
    const f16x8 qfB0 = *(const f16x8*)(hb + qB * 64 + lg * 8);
    const f16x8 qfB1 = *(const f16x8*)(hb + qB * 64 + 32 + lg * 8);

    // constant 5th V-row A-fragment: ones iff ll==0
    f16x8 vone;
    {
        const _Float16 o = (ll == 0) ? (_Float16)1.0f : (_Float16)0.0f;
        #pragma unroll
        for (int j = 0; j < 8; ++j) vone[j] = o;
    }

    f32x4 OaccA[4] = {{0.f,0.f,0.f,0.f},{0.f,0.f,0.f,0.f},{0.f,0.f,0.f,0.f},{0.f,0.f,0.f,0.f}};
    f32x4 OaccB[4] = {{0.f,0.f,0.f,0.f},{0.f,0.f,0.f,0.f},{0.f,0.f,0.f,0.f},{0.f,0.f,0.f,0.f}};
    f32x4 Oacc4A = {0.f, 0.f, 0.f, 0.f};
    f32x4 Oacc4B = {0.f, 0.f, 0.f, 0.f};
    float m_runA = NEGINF, m_runB = NEGINF;
    float mmA = NEGINF * LOG2E, mmB = NEGINF * LOG2E;
    float negv = NEGINF;

    // staging mapping: 512 threads, thread stages 8 K elems + 8 V elems
    const int sr  = tid >> 3;          // 0..63
    const int sc8 = (tid & 7) * 8;     // 0..56
    const int srp = (sr & 0x23) | ((sr & 0x18) >> 1) | ((sr & 0x4) << 2);

    const int kw = srp * 128 + ((sc8 * 2) ^ ((srp & 7) << 4));
    const int vw = sr  * 128 + ((sc8 * 2) ^ ((sr  & 7) << 4));
    const int rb0 = ll * 128 + (((lg * 16))      ^ ((ll & 7) << 4));
    const int rb1 = ll * 128 + (((64 + lg * 16)) ^ ((ll & 7) << 4));

    char* const KB = (char*)Kl;
    char* const VB = (char*)Vt;

    const _Float16* gK = hb  + (long)(kv_base + sr) * 64 + sc8;
    const _Float16* gV = hTb + (long)sr * kN + kv_base + sc8;

    // wave-uniform lane-mask pointers (one per q16 group)
    const int wuni = __builtin_amdgcn_readfirstlane(wave);
    const uint64_t* __restrict__ wmpA =
        wmask + ((long)(blockIdx.x * 16 + wuni * 2) * 64 + (kv_base >> 6)) * 16;
    const uint64_t* __restrict__ wmpB = wmpA + (long)64 * 16;

    // ---- stage tile 0 ----
    {
        const f16x8 a0 = *(const f16x8*)(gK);
        const f16x8 b0 = *(const f16x8*)(gV);
        *(f16x8*)(KB + kw) = a0;
        *(f16x8*)(VB + vw) = b0;
        gK += 64 * 64;  gV += 64;
    }

    union PF { half2_t hh[4]; f16x8 v; };

#define SOFTMAX_FRAG(S_, WM_, OACC_, OACC4_, MRUN_, MM_, PF1_, PF2_)             \
    do {                                                                         \
        _Pragma("unroll")                                                        \
        for (int t = 0; t < 4; ++t) {                                            \
            _Pragma("unroll")                                                    \
            for (int rr = 0; rr < 4; ++rr) {                                     \
                float sv = S_[t][rr];                                            \
                asm("v_cndmask_b32 %0, %1, %2, %3"                               \
                    : "=v"(sv) : "v"(negv), "v"(sv), "s"(WM_[t * 4 + rr]));      \
                S_[t][rr] = sv;                                                  \
            }                                                                    \
        }                                                                        \
        float mx0 = fmaxf(fmaxf(S_[0][0], S_[0][1]), fmaxf(S_[0][2], S_[0][3])); \
        float mx1 = fmaxf(fmaxf(S_[1][0], S_[1][1]), fmaxf(S_[1][2], S_[1][3])); \
        float mx2 = fmaxf(fmaxf(S_[2][0], S_[2][1]), fmaxf(S_[2][2], S_[2][3])); \
        float mx3 = fmaxf(fmaxf(S_[3][0], S_[3][1]), fmaxf(S_[3][2], S_[3][3])); \
        float mloc = fmaxf(fmaxf(mx0, mx1), fmaxf(mx2, mx3));                    \
        mloc = fmaxf(mloc, __shfl_xor(mloc, 16));                                \
        mloc = fmaxf(mloc, __shfl_xor(mloc, 32));                                \
        if (__any(mloc > MRUN_ + 8.f)) {                                         \
            const float mnew = fmaxf(MRUN_, mloc);                               \
            const float scl  = __builtin_amdgcn_exp2f((MRUN_ - mnew) * LOG2E);   \
            MRUN_ = mnew;                                                        \
            MM_   = mnew * LOG2E;                                                \
            _Pragma("unroll")                                                    \
            for (int dt = 0; dt < 4; ++dt) OACC_[dt] *= scl;                     \
            OACC4_ *= scl;                                                       \
        }                                                                        \
        _Pragma("unroll")                                                        \
        for (int t = 0; t < 4; ++t) {                                            \
            _Pragma("unroll")                                                    \
            for (int rr = 0; rr < 4; ++rr)                                       \
                S_[t][rr] = __builtin_amdgcn_exp2f(fmaf(S_[t][rr], LOG2E, -MM_));\
        }                                                                        \
        PF1_.hh[0] = __builtin_amdgcn_cvt_pkrtz(S_[0][0], S_[0][1]);             \
        PF1_.hh[1] = __builtin_amdgcn_cvt_pkrtz(S_[0][2], S_[0][3]);             \
        PF1_.hh[2] = __builtin_amdgcn_cvt_pkrtz(S_[1][0], S_[1][1]);             \
        PF1_.hh[3] = __builtin_amdgcn_cvt_pkrtz(S_[1][2], S_[1][3]);             \
        PF2_.hh[0] = __builtin_amdgcn_cvt_pkrtz(S_[2][0], S_[2][1]);             \
        PF2_.hh[1] = __builtin_amdgcn_cvt_pkrtz(S_[2][2], S_[2][3]);             \
        PF2_.hh[2] = __builtin_amdgcn_cvt_pkrtz(S_[3][0], S_[3][1]);             \
        PF2_.hh[3] = __builtin_amdgcn_cvt_pkrtz(S_[3][2], S_[3][3]);             \
    } while (0)

#define TILE_BODY(IT, CB, NB)                                                    \
    do {                                                                         \
        const int it_ = (IT);                                                    \
        /* issue next tile's global loads (vmcnt) BEFORE the barrier */          \
        f16x8 nk0{}, nv0{};                                                      \
        if (it_ + 1 < NT) {                                                      \
            nk0 = *(const f16x8*)(gK);                                           \
            nv0 = *(const f16x8*)(gV);                                           \
            gK += 64 * 64;  gV += 64;                                            \
        }                                                                        \
        /* raw barrier: drain LDS only; vmcnt stays in flight */                 \
        asm volatile("s_waitcnt lgkmcnt(0)" ::: "memory");                       \
        __builtin_amdgcn_s_barrier();                                            \
        __builtin_amdgcn_sched_barrier(0);                                       \
        /* current tile's lane-masks (s_load; QK below covers latency) */        \
        uint64_t WMA[16], WMB[16];                                               \
        _Pragma("unroll")                                                        \
        for (int s5 = 0; s5 < 16; ++s5) WMA[s5] = wmpA[(long)it_ * 16 + s5];     \
        _Pragma("unroll")                                                        \
        for (int s5 = 0; s5 < 16; ++s5) WMB[s5] = wmpB[(long)it_ * 16 + s5];     \
        /* QK: each k-read feeds BOTH fragments */                               \
        f32x4 SA[4], SB[4];                                                      \
        __builtin_amdgcn_s_setprio(1);                                           \
        _Pragma("unroll")                                                        \
        for (int t = 0; t < 4; ++t) {                                            \
            const f16x8 k0 = *(const f16x8*)(KB + (CB) + rb0 + t * 2048);        \
            const f16x8 k1 = *(const f16x8*)(KB + (CB) + rb1 + t * 2048);        \
            f32x4 sa = {0.f, 0.f, 0.f, 0.f};                                     \
            f32x4 sb = {0.f, 0.f, 0.f, 0.f};                                     \
            sa = __builtin_amdgcn_mfma_f32_16x16x32_f16(k0, qfA0, sa, 0, 0, 0);  \
            sa = __builtin_amdgcn_mfma_f32_16x16x32_f16(k1, qfA1, sa, 0, 0, 0);  \
            sb = __builtin_amdgcn_mfma_f32_16x16x32_f16(k0, qfB0, sb, 0, 0, 0);  \
            sb = __builtin_amdgcn_mfma_f32_16x16x32_f16(k1, qfB1, sb, 0, 0, 0);  \
            SA[t] = sa;                                                          \
            SB[t] = sb;                                                          \
        }                                                                        \
        __builtin_amdgcn_s_setprio(0);                                           \
        /* write prefetched tile to the other buffer */                          \
        if (it_ + 1 < NT) {                                                      \
            *(f16x8*)(KB + (NB) + kw) = nk0;                                     \
            *(f16x8*)(VB + (NB) + vw) = nv0;                                     \
        }                                                                        \
        PF pfA1, pfA2, pfB1, pfB2;                                               \
        SOFTMAX_FRAG(SA, WMA, OaccA, Oacc4A, m_runA, mmA, pfA1, pfA2);           \
        SOFTMAX_FRAG(SB, WMB, OaccB, Oacc4B, m_runB, mmB, pfB1, pfB2);           \
        /* PV: each v-read feeds BOTH fragments */                               \
        __builtin_amdgcn_s_setprio(1);                                           \
        _Pragma("unroll")                                                        \
        for (int dt = 0; dt < 4; ++dt) {                                         \
            const f16x8 v0 = *(const f16x8*)(VB + (CB) + rb0 + dt * 2048);       \
            const f16x8 v1 = *(const f16x8*)(VB + (CB) + rb1 + dt * 2048);       \
            OaccA[dt] = __builtin_amdgcn_mfma_f32_16x16x32_f16(v0, pfA1.v, OaccA[dt], 0, 0, 0); \
            OaccA[dt] = __builtin_amdgcn_mfma_f32_16x16x32_f16(v1, pfA2.v, OaccA[dt], 0, 0, 0); \
            OaccB[dt] = __builtin_amdgcn_mfma_f32_16x16x32_f16(v0, pfB1.v, OaccB[dt], 0, 0, 0); \
            OaccB[dt] = __builtin_amdgcn_mfma_f32_16x16x32_f16(v1, pfB2.v, OaccB[dt], 0, 0, 0); \
        }                                                                        \
        Oacc4A = __builtin_amdgcn_mfma_f32_16x16x32_f16(vone, pfA1.v, Oacc4A, 0, 0, 0); \
        Oacc4A = __builtin_amdgcn_mfma_f32_16x16x32_f16(vone, pfA2.v, Oacc4A, 0, 0, 0); \
        Oacc4B = __builtin_amdgcn_mfma_f32_16x16x32_f16(vone, pfB1.v, Oacc4B, 0, 0, 0); \
        Oacc4B = __builtin_amdgcn_mfma_f32_16x16x32_f16(vone, pfB2.v, Oacc4B, 0, 0, 0); \
        __builtin_amdgcn_s_setprio(0);                                           \
    } while (0)

    for (int ith = 0; ith < NT; ith += 2) {
        TILE_BODY(ith,     0,    8192);
        TILE_BODY(ith + 1, 8192, 0);
    }
#undef TILE_BODY
#undef SOFTMAX_FRAG

    // ---- l broadcast ----
    const float lsumA = __shfl(Oacc4A[0], ll, 64);
    const float lsumB = __shfl(Oacc4B[0], ll, 64);
    const float invA  = (lsumA > 0.f) ? (1.0f / lsumA) : 0.f;
    const float invB  = (lsumB > 0.f) ? (1.0f / lsumB) : 0.f;

    // ---- epilogue: lane owns q = {qA, qB}, d = 16*dt + 4*lg + rr ----
    if (outp != nullptr) {
        #pragma unroll
        for (int dt = 0; dt < 4; ++dt) {
            const int dbase = dt * 16 + lg * 4;
            const f32x4 bv = *(const f32x4*)(bias + dbase);
            f32x4 oa, ob;
            #pragma unroll
            for (int rr = 0; rr < 4; ++rr) {
                oa[rr] = OaccA[dt][rr] * invA + bv[rr];
                ob[rr] = OaccB[dt][rr] * invB + bv[rr];
            }
            *(f32x4*)(outp + ((long)b * kN + qA) * 64 + dbase) = oa;
            *(f32x4*)(outp + ((long)b * kN + qB) * 64 + dbase) = ob;
        }
    } else {
        const long srowA = (long)split * kB * kN + (long)b * kN + qA;
        const long srowB = srowA + 16;
        #pragma unroll
        for (int dt = 0; dt < 4; ++dt) {
            const int dbase = dt * 16 + lg * 4;
            f16x4 pa, pb;
            #pragma unroll
            for (int rr = 0; rr < 4; ++rr) {
                pa[rr] = (_Float16)(OaccA[dt][rr] * invA);
                pb[rr] = (_Float16)(OaccB[dt][rr] * invB);
            }
            *(f16x4*)(pO + srowA * 64 + dbase) = pa;
            *(f16x4*)(pO + srowB * 64 + dbase) = pb;
        }
        if (lane < 16) {
            pml[srowA * 2 + 0] = m_runA;
            pml[srowA * 2 + 1] = lsumA;
            pml[srowB * 2 + 0] = m_runB;
            pml[srowB * 2 + 1] = lsumB;
        }
    }
}

// ---------------------------------------------------------------------------
// Kernel 4: combine split-KV partials (normalized f16; weight = l*e^(m-M)).
// ---------------------------------------------------------------------------
__global__ __launch_bounds__(256) void combine_kernel(const _Float16* __restrict__ pO,
                                                      const float* __restrict__ pml,
                                                      const float* __restrict__ bias,
                                                      float* __restrict__ outp,
                                                      int ks)
{
    const long idx = (long)blockIdx.x * 256 + threadIdx.x;  // B*N*16 groups
    const long row = idx >> 4;
    const int  d4  = (int)(idx & 15) * 4;

    float M = NEGINF;
    for (int s = 0; s < ks; ++s)
        M = fmaxf(M, pml[((long)s * kB * kN + row) * 2]);

    float L = 0.f;
    f32x4 acc = {0.f, 0.f, 0.f, 0.f};
    for (int s = 0; s < ks; ++s) {
        const long srow = (long)s * kB * kN + row;
        const float m = pml[srow * 2 + 0];
        const float l = pml[srow * 2 + 1];
        const float w = l * __builtin_amdgcn_exp2f((m - M) * LOG2E);
        L += w;
        const f16x4 o = *(const f16x4*)(pO + srow * 64 + d4);
        #pragma unroll
        for (int j = 0; j < 4; ++j) acc[j] += (float)o[j] * w;
    }
    const float invL = (L > 0.f) ? (1.0f / L) : 0.f;
    const f32x4 bv = *(const f32x4*)(bias + d4);
    *(f32x4*)(outp + row * 64 + d4) = acc * invL + bv;
}

// ---------------------------------------------------------------------------
extern "C" void kernel_launch(void* const* d_in, const int* in_sizes, int n_in,
                              void* d_out, int out_size, void* d_ws, size_t ws_size,
                              hipStream_t stream) {
    const float*  x     = (const float*)d_in[0];   // [8,4096,64]
    const int*    graph = (const int*)d_in[1];     // [4096,4096]
    const float*  W     = (const float*)d_in[2];   // [64,64]
    const float*  bias  = (const float*)d_in[3];   // [64]
    float*        outp  = (float*)d_out;

    char* ws = (char*)d_ws;
    _Float16* hptr  = (_Float16*)ws;                          // 4 MiB @ 0
    _Float16* hTptr = (_Float16*)(ws + (4u << 20));           // 4 MiB @ 4M
    uint64_t* wmptr = (uint64_t*)(ws + (8u << 20));           // 2 MiB @ 8M

    // pO: ks * 4 MiB (f16 normalized), pml: ks * 256 KiB  @ 10M
    int ks = 1;
    if      (ws_size >= ((size_t)47 << 20)) ks = 8;
    else if (ws_size >= ((size_t)28 << 20)) ks = 4;
    else if (ws_size >= ((size_t)19 << 20)) ks = 2;

    _Float16* pO  = (_Float16*)(ws + (10u << 20));
    float*    pml = (float*)(ws + (10u << 20) + (size_t)ks * (4u << 20));

    hproj_kernel<<<dim3(kB * kN / 64), dim3(256), 0, stream>>>(x, W, hptr, hTptr);
    graphmask_kernel<<<dim3(256 * 64 / 4), dim3(256), 0, stream>>>(graph, wmptr);

    if (ks == 1) {
        attn_kernel<<<dim3(kN / 256, kB, 1), dim3(512), 0, stream>>>(
            hptr, hTptr, wmptr, bias, outp, nullptr, nullptr, kN);
    } else {
        attn_kernel<<<dim3(kN / 256, kB, ks), dim3(512), 0, stream>>>(
            hptr, hTptr, wmptr, bias, nullptr, pO, pml, kN / ks);
        combine_kernel<<<dim3(kB * kN * 16 / 256), dim3(256), 0, stream>>>(
            pO, pml, bias, outp, ks);
    }
}

// Round 16
// 80.851 us; speedup vs baseline: 1.0870x; 1.0870x over previous
//
#include <hip/hip_runtime.h>
#include <stdint.h>

typedef _Float16 f16x8 __attribute__((ext_vector_type(8)));
typedef _Float16 f16x4 __attribute__((ext_vector_type(4)));
typedef __fp16 half2_t __attribute__((ext_vector_type(2)));
typedef float f32x4 __attribute__((ext_vector_type(4)));

#define LOG2E 1.44269504088896340736f
#define NEGINF (-1e16f)

constexpr int kN = 4096;   // nodes
constexpr int kD = 64;     // feature dim
constexpr int kB = 8;      // batch

// ---------------------------------------------------------------------------
// Kernel 1: h[row][d] = sum_c x[row][c] * W[d][c]  (f32 math, f16 store)
//           also writes hT[b][d][n] via LDS transpose (coalesced stores)
// ---------------------------------------------------------------------------
__global__ __launch_bounds__(256) void hproj_kernel(const float* __restrict__ x,
                                                    const float* __restrict__ W,
                                                    _Float16* __restrict__ hout,
                                                    _Float16* __restrict__ hTout)
{
    __shared__ float Wt[64][64];   // Wt[c][d] = W[d][c]
    __shared__ float xs[64][65];
    __shared__ _Float16 ht[64][68];  // h tile for transpose, padded

    const int tid = threadIdx.x;
    const int r   = tid >> 2;          // 0..63
    const int c0  = (tid & 3) * 16;    // 0,16,32,48

    #pragma unroll
    for (int j = 0; j < 16; j += 4) {
        const float4 v = *(const float4*)(W + r * 64 + c0 + j);
        Wt[c0 + j + 0][r] = v.x;
        Wt[c0 + j + 1][r] = v.y;
        Wt[c0 + j + 2][r] = v.z;
        Wt[c0 + j + 3][r] = v.w;
    }
    const long rowbase = (long)blockIdx.x * 64;
    #pragma unroll
    for (int j = 0; j < 16; j += 4) {
        const float4 v = *(const float4*)(x + (rowbase + r) * 64 + c0 + j);
        xs[r][c0 + j + 0] = v.x;
        xs[r][c0 + j + 1] = v.y;
        xs[r][c0 + j + 2] = v.z;
        xs[r][c0 + j + 3] = v.w;
    }
    __syncthreads();

    const int d0 = (tid & 3) * 16;
    f32x4 acc[4] = {{0.f,0.f,0.f,0.f},{0.f,0.f,0.f,0.f},{0.f,0.f,0.f,0.f},{0.f,0.f,0.f,0.f}};
    #pragma unroll 4
    for (int c = 0; c < 64; ++c) {
        const float xv = xs[r][c];
        const f32x4* wrow = (const f32x4*)&Wt[c][d0];
        #pragma unroll
        for (int k = 0; k < 4; ++k) acc[k] += wrow[k] * xv;
    }
    f16x8 o0, o1;
    #pragma unroll
    for (int j = 0; j < 8; ++j) {
        o0[j] = (_Float16)acc[j >> 2][j & 3];
        o1[j] = (_Float16)acc[2 + (j >> 2)][j & 3];
    }
    *(f16x8*)(hout + (rowbase + r) * 64 + d0)     = o0;
    *(f16x8*)(hout + (rowbase + r) * 64 + d0 + 8) = o1;

    // LDS transpose for hT
    #pragma unroll
    for (int j = 0; j < 8; ++j) {
        ht[r][d0 + j]     = o0[j];
        ht[r][d0 + 8 + j] = o1[j];
    }
    __syncthreads();

    const int bb = blockIdx.x >> 6;                 // 64 blocks per batch
    const int n0 = (int)(rowbase & (kN - 1));
    const int dr = tid >> 2;                        // output d row
    const int c4 = (tid & 3) * 16;                  // n-column group
    f16x8 t0, t1;
    #pragma unroll
    for (int j = 0; j < 8; ++j) {
        t0[j] = ht[c4 + j][dr];
        t1[j] = ht[c4 + 8 + j][dr];
    }
    _Float16* dst = hTout + (long)bb * kD * kN + (long)dr * kN + n0 + c4;
    *(f16x8*)(dst)     = t0;
    *(f16x8*)(dst + 8) = t1;
}

// ---------------------------------------------------------------------------
// Kernel 2 (fused): graph (int32 0/1) -> per-slot 64-bit LANE masks directly.
// wm[(q16*64 + kv64)*16 + s]: bit for lane l=(lg*16+ll) =
//   graph[q16*16+ll][kv64*64 + (t>=2?32:0) + 8*lg + 4*(t&1) + rr],  s=t*4+rr
// ---------------------------------------------------------------------------
__global__ __launch_bounds__(256) void graphmask_kernel(const int* __restrict__ g,
                                                        uint64_t* __restrict__ wmout)
{
    const int tid  = threadIdx.x;
    const int wv   = tid >> 6;
    const int lane = tid & 63;
    const int ll   = lane & 15;
    const int lg   = lane >> 4;
    const int pair = blockIdx.x * 4 + wv;          // 0..16383
    const int q16  = pair >> 6;
    const int kv64 = pair & 63;

    const int* gr = g + (long)(q16 * 16 + ll) * kN + kv64 * 64 + 8 * lg;
    const int4 u0 = *(const int4*)(gr);            // cols 8lg+0..3
    const int4 u1 = *(const int4*)(gr + 4);        // cols 8lg+4..7
    const int4 u2 = *(const int4*)(gr + 32);       // cols 32+8lg+0..3
    const int4 u3 = *(const int4*)(gr + 36);       // cols 32+8lg+4..7

    int gv[16];
    gv[0] = u0.x;  gv[1] = u0.y;  gv[2] = u0.z;  gv[3] = u0.w;
    gv[4] = u1.x;  gv[5] = u1.y;  gv[6] = u1.z;  gv[7] = u1.w;
    gv[8] = u2.x;  gv[9] = u2.y;  gv[10] = u2.z;  gv[11] = u2.w;
    gv[12] = u3.x; gv[13] = u3.y; gv[14] = u3.z;  gv[15] = u3.w;

    uint64_t Wb[16];
    #pragma unroll
    for (int s = 0; s < 16; ++s) {
        const int t = s >> 2, rr = s & 3;
        const int j = (t >= 2 ? 8 : 0) + 4 * (t & 1) + rr;   // index into gv
        Wb[s] = __ballot(gv[j] != 0);
    }

    const int s = lane;
    uint64_t a0 = (s & 1) ? Wb[1]  : Wb[0];
    uint64_t a1 = (s & 1) ? Wb[3]  : Wb[2];
    uint64_t a2 = (s & 1) ? Wb[5]  : Wb[4];
    uint64_t a3 = (s & 1) ? Wb[7]  : Wb[6];
    uint64_t a4 = (s & 1) ? Wb[9]  : Wb[8];
    uint64_t a5 = (s & 1) ? Wb[11] : Wb[10];
    uint64_t a6 = (s & 1) ? Wb[13] : Wb[12];
    uint64_t a7 = (s & 1) ? Wb[15] : Wb[14];
    uint64_t b0 = (s & 2) ? a1 : a0;
    uint64_t b1 = (s & 2) ? a3 : a2;
    uint64_t b2 = (s & 2) ? a5 : a4;
    uint64_t b3 = (s & 2) ? a7 : a6;
    uint64_t c0 = (s & 4) ? b1 : b0;
    uint64_t c1 = (s & 4) ? b3 : b2;
    uint64_t v  = (s & 8) ? c1 : c0;
    if (lane < 16) wmout[(long)pair * 16 + lane] = v;
}

// ---------------------------------------------------------------------------
// Kernel 3: swapped-operand flash attention, 32-q waves (r14-proven body).
// grid (16, 8, 4), 512 thr (8 waves); wave handles 32 q rows (block: 256).
// ---------------------------------------------------------------------------
__global__ __launch_bounds__(512, 4) void attn_kernel(const _Float16* __restrict__ h,
                                                      const _Float16* __restrict__ hT,
                                                      const uint64_t* __restrict__ wmask,
                                                      const float* __restrict__ bias,
                                                      float* __restrict__ outp,
                                                      _Float16* __restrict__ pO,
                                                      float* __restrict__ pml,
                                                      int kvlen)
{
    __shared__ alignas(16) char Kl[2][8192];
    __shared__ alignas(16) char Vt[2][8192];

    const int b     = blockIdx.y;
    const int split = blockIdx.z;
    const int q0    = blockIdx.x * 256;
    const int tid   = threadIdx.x;
    const int wave  = tid >> 6;
    const int lane  = tid & 63;
    const int lg    = lane >> 4;   // 0..3
    const int ll    = lane & 15;   // 0..15

    const _Float16* hb  = h  + (long)b * kN * kD;
    const _Float16* hTb = hT + (long)b * kD * kN;
    const int kv_base = split * kvlen;
    const int NT      = kvlen / 64;

    // Dual Q fragments: frag A = q rows [wave*32, +16), frag B = [+16, +32)
    const int qA = q0 + wave * 32 + ll;
    const int qB = qA + 16;
    const f16x8 qfA0 = *(const f16x8*)(hb + qA * 64 + lg * 8);
    const f16x8 qfA1 = *(const f16x8*)(hb + qA * 64 + 32 + lg * 8);
    const f16x8 qfB0 = *(const f16x8*)(hb + qB * 64 + lg * 8);
    const f16x8 qfB1 = *(const f16x8*)(hb + qB * 64 + 32 + lg * 8);

    // constant 5th V-row A-fragment: ones iff ll==0
    f16x8 vone;
    {
        const _Float16 o = (ll == 0) ? (_Float16)1.0f : (_Float16)0.0f;
        #pragma unroll
        for (int j = 0; j < 8; ++j) vone[j] = o;
    }

    f32x4 OaccA[4] = {{0.f,0.f,0.f,0.f},{0.f,0.f,0.f,0.f},{0.f,0.f,0.f,0.f},{0.f,0.f,0.f,0.f}};
    f32x4 OaccB[4] = {{0.f,0.f,0.f,0.f},{0.f,0.f,0.f,0.f},{0.f,0.f,0.f,0.f},{0.f,0.f,0.f,0.f}};
    f32x4 Oacc4A = {0.f, 0.f, 0.f, 0.f};
    f32x4 Oacc4B = {0.f, 0.f, 0.f, 0.f};
    float m_runA = NEGINF, m_runB = NEGINF;
    float mmA = NEGINF * LOG2E, mmB = NEGINF * LOG2E;
    float negv = NEGINF;

    // staging mapping: 512 threads, thread stages 8 K elems + 8 V elems
    const int sr  = tid >> 3;          // 0..63
    const int sc8 = (tid & 7) * 8;     // 0..56
    const int srp = (sr & 0x23) | ((sr & 0x18) >> 1) | ((sr & 0x4) << 2);

    const int kw = srp * 128 + ((sc8 * 2) ^ ((srp & 7) << 4));
    const int vw = sr  * 128 + ((sc8 * 2) ^ ((sr  & 7) << 4));
    const int rb0 = ll * 128 + (((lg * 16))      ^ ((ll & 7) << 4));
    const int rb1 = ll * 128 + (((64 + lg * 16)) ^ ((ll & 7) << 4));

    char* const KB = (char*)Kl;
    char* const VB = (char*)Vt;

    const _Float16* gK = hb  + (long)(kv_base + sr) * 64 + sc8;
    const _Float16* gV = hTb + (long)sr * kN + kv_base + sc8;

    // wave-uniform lane-mask pointers (one per q16 group)
    const int wuni = __builtin_amdgcn_readfirstlane(wave);
    const uint64_t* __restrict__ wmpA =
        wmask + ((long)(blockIdx.x * 16 + wuni * 2) * 64 + (kv_base >> 6)) * 16;
    const uint64_t* __restrict__ wmpB = wmpA + (long)64 * 16;

    // ---- stage tile 0 ----
    {
        const f16x8 a0 = *(const f16x8*)(gK);
        const f16x8 b0 = *(const f16x8*)(gV);
        *(f16x8*)(KB + kw) = a0;
        *(f16x8*)(VB + vw) = b0;
        gK += 64 * 64;  gV += 64;
    }

    union PF { half2_t hh[4]; f16x8 v; };

#define SOFTMAX_FRAG(S_, WM_, OACC_, OACC4_, MRUN_, MM_, PF1_, PF2_)             \
    do {                                                                         \
        _Pragma("unroll")                                                        \
        for (int t = 0; t < 4; ++t) {                                            \
            _Pragma("unroll")                                                    \
            for (int rr = 0; rr < 4; ++rr) {                                     \
                float sv = S_[t][rr];                                            \
                asm("v_cndmask_b32 %0, %1, %2, %3"                               \
                    : "=v"(sv) : "v"(negv), "v"(sv), "s"(WM_[t * 4 + rr]));      \
                S_[t][rr] = sv;                                                  \
            }                                                                    \
        }                                                                        \
        float mx0 = fmaxf(fmaxf(S_[0][0], S_[0][1]), fmaxf(S_[0][2], S_[0][3])); \
        float mx1 = fmaxf(fmaxf(S_[1][0], S_[1][1]), fmaxf(S_[1][2], S_[1][3])); \
        float mx2 = fmaxf(fmaxf(S_[2][0], S_[2][1]), fmaxf(S_[2][2], S_[2][3])); \
        float mx3 = fmaxf(fmaxf(S_[3][0], S_[3][1]), fmaxf(S_[3][2], S_[3][3])); \
        float mloc = fmaxf(fmaxf(mx0, mx1), fmaxf(mx2, mx3));                    \
        mloc = fmaxf(mloc, __shfl_xor(mloc, 16));                                \
        mloc = fmaxf(mloc, __shfl_xor(mloc, 32));                                \
        if (__any(mloc > MRUN_ + 8.f)) {                                         \
            const float mnew = fmaxf(MRUN_, mloc);                               \
            const float scl  = __builtin_amdgcn_exp2f((MRUN_ - mnew) * LOG2E);   \
            MRUN_ = mnew;                                                        \
            MM_   = mnew * LOG2E;                                                \
            _Pragma("unroll")                                                    \
            for (int dt = 0; dt < 4; ++dt) OACC_[dt] *= scl;                     \
            OACC4_ *= scl;                                                       \
        }                                                                        \
        _Pragma("unroll")                                                        \
        for (int t = 0; t < 4; ++t) {                                            \
            _Pragma("unroll")                                                    \
            for (int rr = 0; rr < 4; ++rr)                                       \
                S_[t][rr] = __builtin_amdgcn_exp2f(fmaf(S_[t][rr], LOG2E, -MM_));\
        }                                                                        \
        PF1_.hh[0] = __builtin_amdgcn_cvt_pkrtz(S_[0][0], S_[0][1]);             \
        PF1_.hh[1] = __builtin_amdgcn_cvt_pkrtz(S_[0][2], S_[0][3]);             \
        PF1_.hh[2] = __builtin_amdgcn_cvt_pkrtz(S_[1][0], S_[1][1]);             \
        PF1_.hh[3] = __builtin_amdgcn_cvt_pkrtz(S_[1][2], S_[1][3]);             \
        PF2_.hh[0] = __builtin_amdgcn_cvt_pkrtz(S_[2][0], S_[2][1]);             \
        PF2_.hh[1] = __builtin_amdgcn_cvt_pkrtz(S_[2][2], S_[2][3]);             \
        PF2_.hh[2] = __builtin_amdgcn_cvt_pkrtz(S_[3][0], S_[3][1]);             \
        PF2_.hh[3] = __builtin_amdgcn_cvt_pkrtz(S_[3][2], S_[3][3]);             \
    } while (0)

#define TILE_BODY(IT, CB, NB)                                                    \
    do {                                                                         \
        const int it_ = (IT);                                                    \
        /* issue next tile's global loads (vmcnt) BEFORE the barrier */          \
        f16x8 nk0{}, nv0{};                                                      \
        if (it_ + 1 < NT) {                                                      \
            nk0 = *(const f16x8*)(gK);                                           \
            nv0 = *(const f16x8*)(gV);                                           \
            gK += 64 * 64;  gV += 64;                                            \
        }                                                                        \
        /* raw barrier: drain LDS only; vmcnt stays in flight */                 \
        asm volatile("s_waitcnt lgkmcnt(0)" ::: "memory");                       \
        __builtin_amdgcn_s_barrier();                                            \
        __builtin_amdgcn_sched_barrier(0);                                       \
        /* current tile's lane-masks (s_load; QK below covers latency) */        \
        uint64_t WMA[16], WMB[16];                                               \
        _Pragma("unroll")                                                        \
        for (int s5 = 0; s5 < 16; ++s5) WMA[s5] = wmpA[(long)it_ * 16 + s5];     \
        _Pragma("unroll")                                                        \
        for (int s5 = 0; s5 < 16; ++s5) WMB[s5] = wmpB[(long)it_ * 16 + s5];     \
        /* QK: each k-read feeds BOTH fragments */                               \
        f32x4 SA[4], SB[4];                                                      \
        __builtin_amdgcn_s_setprio(1);                                           \
        _Pragma("unroll")                                                        \
        for (int t = 0; t < 4; ++t) {                                            \
            const f16x8 k0 = *(const f16x8*)(KB + (CB) + rb0 + t * 2048);        \
            const f16x8 k1 = *(const f16x8*)(KB + (CB) + rb1 + t * 2048);        \
            f32x4 sa = {0.f, 0.f, 0.f, 0.f};                                     \
            f32x4 sb = {0.f, 0.f, 0.f, 0.f};                                     \
            sa = __builtin_amdgcn_mfma_f32_16x16x32_f16(k0, qfA0, sa, 0, 0, 0);  \
            sa = __builtin_amdgcn_mfma_f32_16x16x32_f16(k1, qfA1, sa, 0, 0, 0);  \
            sb = __builtin_amdgcn_mfma_f32_16x16x32_f16(k0, qfB0, sb, 0, 0, 0);  \
            sb = __builtin_amdgcn_mfma_f32_16x16x32_f16(k1, qfB1, sb, 0, 0, 0);  \
            SA[t] = sa;                                                          \
            SB[t] = sb;                                                          \
        }                                                                        \
        __builtin_amdgcn_s_setprio(0);                                           \
        /* write prefetched tile to the other buffer */                          \
        if (it_ + 1 < NT) {                                                      \
            *(f16x8*)(KB + (NB) + kw) = nk0;                                     \
            *(f16x8*)(VB + (NB) + vw) = nv0;                                     \
        }                                                                        \
        PF pfA1, pfA2, pfB1, pfB2;                                               \
        SOFTMAX_FRAG(SA, WMA, OaccA, Oacc4A, m_runA, mmA, pfA1, pfA2);           \
        SOFTMAX_FRAG(SB, WMB, OaccB, Oacc4B, m_runB, mmB, pfB1, pfB2);           \
        /* PV: each v-read feeds BOTH fragments */                               \
        __builtin_amdgcn_s_setprio(1);                                           \
        _Pragma("unroll")                                                        \
        for (int dt = 0; dt < 4; ++dt) {                                         \
            const f16x8 v0 = *(const f16x8*)(VB + (CB) + rb0 + dt * 2048);       \
            const f16x8 v1 = *(const f16x8*)(VB + (CB) + rb1 + dt * 2048);       \
            OaccA[dt] = __builtin_amdgcn_mfma_f32_16x16x32_f16(v0, pfA1.v, OaccA[dt], 0, 0, 0); \
            OaccA[dt] = __builtin_amdgcn_mfma_f32_16x16x32_f16(v1, pfA2.v, OaccA[dt], 0, 0, 0); \
            OaccB[dt] = __builtin_amdgcn_mfma_f32_16x16x32_f16(v0, pfB1.v, OaccB[dt], 0, 0, 0); \
            OaccB[dt] = __builtin_amdgcn_mfma_f32_16x16x32_f16(v1, pfB2.v, OaccB[dt], 0, 0, 0); \
        }                                                                        \
        Oacc4A = __builtin_amdgcn_mfma_f32_16x16x32_f16(vone, pfA1.v, Oacc4A, 0, 0, 0); \
        Oacc4A = __builtin_amdgcn_mfma_f32_16x16x32_f16(vone, pfA2.v, Oacc4A, 0, 0, 0); \
        Oacc4B = __builtin_amdgcn_mfma_f32_16x16x32_f16(vone, pfB1.v, Oacc4B, 0, 0, 0); \
        Oacc4B = __builtin_amdgcn_mfma_f32_16x16x32_f16(vone, pfB2.v, Oacc4B, 0, 0, 0); \
        __builtin_amdgcn_s_setprio(0);                                           \
    } while (0)

    for (int ith = 0; ith < NT; ith += 2) {
        TILE_BODY(ith,     0,    8192);
        TILE_BODY(ith + 1, 8192, 0);
    }
#undef TILE_BODY
#undef SOFTMAX_FRAG

    // ---- l broadcast ----
    const float lsumA = __shfl(Oacc4A[0], ll, 64);
    const float lsumB = __shfl(Oacc4B[0], ll, 64);
    const float invA  = (lsumA > 0.f) ? (1.0f / lsumA) : 0.f;
    const float invB  = (lsumB > 0.f) ? (1.0f / lsumB) : 0.f;

    // ---- epilogue: lane owns q = {qA, qB}, d = 16*dt + 4*lg + rr ----
    if (outp != nullptr) {
        #pragma unroll
        for (int dt = 0; dt < 4; ++dt) {
            const int dbase = dt * 16 + lg * 4;
            const f32x4 bv = *(const f32x4*)(bias + dbase);
            f32x4 oa, ob;
            #pragma unroll
            for (int rr = 0; rr < 4; ++rr) {
                oa[rr] = OaccA[dt][rr] * invA + bv[rr];
                ob[rr] = OaccB[dt][rr] * invB + bv[rr];
            }
            *(f32x4*)(outp + ((long)b * kN + qA) * 64 + dbase) = oa;
            *(f32x4*)(outp + ((long)b * kN + qB) * 64 + dbase) = ob;
        }
    } else {
        const long srowA = (long)split * kB * kN + (long)b * kN + qA;
        const long srowB = srowA + 16;
        #pragma unroll
        for (int dt = 0; dt < 4; ++dt) {
            const int dbase = dt * 16 + lg * 4;
            f16x4 pa, pb;
            #pragma unroll
            for (int rr = 0; rr < 4; ++rr) {
                pa[rr] = (_Float16)(OaccA[dt][rr] * invA);
                pb[rr] = (_Float16)(OaccB[dt][rr] * invB);
            }
            *(f16x4*)(pO + srowA * 64 + dbase) = pa;
            *(f16x4*)(pO + srowB * 64 + dbase) = pb;
        }
        if (lane < 16) {
            pml[srowA * 2 + 0] = m_runA;
            pml[srowA * 2 + 1] = lsumA;
            pml[srowB * 2 + 0] = m_runB;
            pml[srowB * 2 + 1] = lsumB;
        }
    }
}

// ---------------------------------------------------------------------------
// Kernel 4: combine split-KV partials (normalized f16; weight = l*e^(m-M)).
// ---------------------------------------------------------------------------
__global__ __launch_bounds__(256) void combine_kernel(const _Float16* __restrict__ pO,
                                                      const float* __restrict__ pml,
                                                      const float* __restrict__ bias,
                                                      float* __restrict__ outp,
                                                      int ks)
{
    const long idx = (long)blockIdx.x * 256 + threadIdx.x;  // B*N*16 groups
    const long row = idx >> 4;
    const int  d4  = (int)(idx & 15) * 4;

    float M = NEGINF;
    for (int s = 0; s < ks; ++s)
        M = fmaxf(M, pml[((long)s * kB * kN + row) * 2]);

    float L = 0.f;
    f32x4 acc = {0.f, 0.f, 0.f, 0.f};
    for (int s = 0; s < ks; ++s) {
        const long srow = (long)s * kB * kN + row;
        const float m = pml[srow * 2 + 0];
        const float l = pml[srow * 2 + 1];
        const float w = l * __builtin_amdgcn_exp2f((m - M) * LOG2E);
        L += w;
        const f16x4 o = *(const f16x4*)(pO + srow * 64 + d4);
        #pragma unroll
        for (int j = 0; j < 4; ++j) acc[j] += (float)o[j] * w;
    }
    const float invL = (L > 0.f) ? (1.0f / L) : 0.f;
    const f32x4 bv = *(const f32x4*)(bias + d4);
    *(f32x4*)(outp + row * 64 + d4) = acc * invL + bv;
}

// ---------------------------------------------------------------------------
extern "C" void kernel_launch(void* const* d_in, const int* in_sizes, int n_in,
                              void* d_out, int out_size, void* d_ws, size_t ws_size,
                              hipStream_t stream) {
    const float*  x     = (const float*)d_in[0];   // [8,4096,64]
    const int*    graph = (const int*)d_in[1];     // [4096,4096]
    const float*  W     = (const float*)d_in[2];   // [64,64]
    const float*  bias  = (const float*)d_in[3];   // [64]
    float*        outp  = (float*)d_out;

    char* ws = (char*)d_ws;
    _Float16* hptr  = (_Float16*)ws;                          // 4 MiB @ 0
    _Float16* hTptr = (_Float16*)(ws + (4u << 20));           // 4 MiB @ 4M
    uint64_t* wmptr = (uint64_t*)(ws + (8u << 20));           // 2 MiB @ 8M

    // pO: ks * 4 MiB (f16 normalized), pml: ks * 256 KiB  @ 10M
    // ks capped at 4: r15 measured ks=8 slower (extra partial traffic,
    // no occupancy gain); r14 measured ks=4 as the best point.
    int ks = 1;
    if      (ws_size >= ((size_t)28 << 20)) ks = 4;
    else if (ws_size >= ((size_t)19 << 20)) ks = 2;

    _Float16* pO  = (_Float16*)(ws + (10u << 20));
    float*    pml = (float*)(ws + (10u << 20) + (size_t)ks * (4u << 20));

    hproj_kernel<<<dim3(kB * kN / 64), dim3(256), 0, stream>>>(x, W, hptr, hTptr);
    graphmask_kernel<<<dim3(256 * 64 / 4), dim3(256), 0, stream>>>(graph, wmptr);

    if (ks == 1) {
        attn_kernel<<<dim3(kN / 256, kB, 1), dim3(512), 0, stream>>>(
            hptr, hTptr, wmptr, bias, outp, nullptr, nullptr, kN);
    } else {
        attn_kernel<<<dim3(kN / 256, kB, ks), dim3(512), 0, stream>>>(
            hptr, hTptr, wmptr, bias, nullptr, pO, pml, kN / ks);
        combine_kernel<<<dim3(kB * kN * 16 / 256), dim3(256), 0, stream>>>(
            pO, pml, bias, outp, ks);
    }
}